// Round 19
// baseline (99.940 us; speedup 1.0000x reference)
//
#include <hip/hip_runtime.h>
#include <hip/hip_bf16.h>

typedef __bf16 bf16x8 __attribute__((ext_vector_type(8)));
typedef float  f32x4  __attribute__((ext_vector_type(4)));
typedef float  f32x16 __attribute__((ext_vector_type(16)));
typedef unsigned short u16x8 __attribute__((ext_vector_type(8)));
typedef unsigned short u16x4 __attribute__((ext_vector_type(4)));
typedef unsigned int   u32x4 __attribute__((ext_vector_type(4)));

#define WAITV(N) asm volatile("s_waitcnt vmcnt(" #N ")" ::: "memory")
#define WAITLG() asm volatile("s_waitcnt lgkmcnt(0)" ::: "memory")
#define SBAR()   do { __builtin_amdgcn_s_barrier(); asm volatile("" ::: "memory"); } while (0)

// ---------- helpers ----------

__device__ __forceinline__ unsigned short f2bf(float f) {
  return __builtin_bit_cast(unsigned short, (__bf16)f);  // RNE via v_cvt
}

__device__ __forceinline__ bf16x8 ld8(const unsigned short* p) {
  return __builtin_bit_cast(bf16x8, *reinterpret_cast<const u16x8*>(p));
}

// packed f32x2 -> bf16x2 (low = a, high = b)
__device__ __forceinline__ unsigned int cvtpk(float a, float b) {
  unsigned int r;
  asm("v_cvt_pk_bf16_f32 %0, %1, %2" : "=v"(r) : "v"(a), "v"(b));
  return r;
}

// raw v_exp_f32: 2^x in one transcendental instr
__device__ __forceinline__ float e2(float x) {
  float r;
  asm("v_exp_f32 %0, %1" : "=v"(r) : "v"(x));
  return r;
}

// async global->LDS, 16B per lane. lds base must be wave-uniform (HW adds lane*16).
__device__ __forceinline__ void gload16(const unsigned short* src, unsigned short* lds) {
  __builtin_amdgcn_global_load_lds(
      (const __attribute__((address_space(1))) unsigned int*)src,
      (__attribute__((address_space(3))) unsigned int*)lds,
      16, 0, 0);
}

// ---------- weight conversion: f32 -> bf16 (x handled inside gemm_qkv, r19) ----------

__global__ __launch_bounds__(256) void cvt_inputs(
    const float* __restrict__ Wq, const float* __restrict__ Wk,
    const float* __restrict__ Wv, const float* __restrict__ Wo,
    unsigned short* __restrict__ wb) {
  const int NWC = 1048576 / 8;   // 131072 = 2^17 chunks per weight
  const int total = 4 * NWC;
  for (int cid = blockIdx.x * 256 + threadIdx.x; cid < total; cid += gridDim.x * 256) {
    const int w = cid >> 17; const int o2 = cid & (NWC - 1);
    const float* s = (w == 0) ? Wq : (w == 1) ? Wk : (w == 2) ? Wv : Wo;
    unsigned short* d = wb + (size_t)w * 1048576;
    const int off = o2 * 8;
    const f32x4 a  = *reinterpret_cast<const f32x4*>(s + off);
    const f32x4 b2 = *reinterpret_cast<const f32x4*>(s + off + 4);
    u16x8 o;
#pragma unroll
    for (int j = 0; j < 4; ++j) { o[j] = f2bf(a[j]); o[j + 4] = f2bf(b2[j]); }
    *reinterpret_cast<u16x8*>(d + off) = o;
  }
}

// ---------- fused QKV GEMM: A reg-staged from f32 x, 3 weight tiles ----------
// 128x64 tile per weight, BK=64 (16 K-steps), 256 threads, 2x2 waves.
// LDS: As 32 KB + Bs 3x16 KB = 80 KB -> 2 blocks/CU. Per step 96 MFMA.
// A path (r19): issue 8x f32x4 loads at phase A (hidden under MFMA), WAITV(0)
// + cvt_pk + 4x ds_write_b128 + lgkmcnt(0) at phase C (T14 issue-early/
// write-late). B path unchanged (6 gload16, pre-swizzled source).
// Outputs: Q,K in qk layout [(b*16+h)*2048+s]*64+d ; V transposed.

__global__ __launch_bounds__(256, 2) void gemm_qkv(
    const float* __restrict__ xf,
    const unsigned short* __restrict__ wb,
    unsigned short* __restrict__ q_s,
    unsigned short* __restrict__ k_s,
    unsigned short* __restrict__ vt_s) {
  __shared__ unsigned short As[2][128 * 64];      // 32 KB
  __shared__ unsigned short Bs[2][3][64 * 64];    // 48 KB
  const int tid  = threadIdx.x;
  const int lane = tid & 63;
  const int g    = lane >> 4;
  const int lo   = lane & 15;
  const int wid  = tid >> 6;
  const int m0   = blockIdx.y * 128;
  const int n0   = blockIdx.x * 64;
  const int wm   = wid >> 1, wn = wid & 1;

  f32x4 acc[3][4][2] = {};    // [weight][mi][ni]
  f32x4 rA[8];                // in-flight A tile (32 f32 = 4 chunks of 8 bf16)

  // A chunk c = i*256+tid: row=c>>3, cc=c&7, content = x chunk scc=cc^(row&7)
  // LDS dest = &As[buf][c*8]  (identical layout to r18's gload16 path)
  auto issueA = [&](int k0) {
#pragma unroll
    for (int i = 0; i < 4; ++i) {
      const int c   = i * 256 + tid;
      const int row = c >> 3, cc = c & 7;
      const int scc = cc ^ (row & 7);
      const float* src = xf + (size_t)(m0 + row) * 1024 + k0 + scc * 8;
      rA[2 * i]     = *reinterpret_cast<const f32x4*>(src);
      rA[2 * i + 1] = *reinterpret_cast<const f32x4*>(src + 4);
    }
  };
  auto writeA = [&](int buf) {
#pragma unroll
    for (int i = 0; i < 4; ++i) {
      const int c = i * 256 + tid;
      u16x8 o;
#pragma unroll
      for (int jx = 0; jx < 4; ++jx) {
        o[jx]     = f2bf(rA[2 * i][jx]);
        o[jx + 4] = f2bf(rA[2 * i + 1][jx]);
      }
      *reinterpret_cast<u16x8*>(&As[buf][c * 8]) = o;   // ds_write_b128, 2-way free
    }
  };
  auto issueB = [&](int buf, int k0) {
#pragma unroll
    for (int w = 0; w < 3; ++w)
#pragma unroll
      for (int i = 0; i < 2; ++i) {
        const int c   = i * 256 + tid;
        const int row = c >> 3, cc = c & 7;
        const int scc = cc ^ (row & 7);
        gload16(wb + (size_t)w * 1048576 + (size_t)(n0 + row) * 1024 + k0 + scc * 8,
                &Bs[buf][w][(i * 4 + wid) * 512]);
      }
  };

  // prologue: tiles 0 and 1 (one-off drain stalls accepted)
  issueA(0);  WAITV(0); writeA(0); issueB(0, 0);
  issueA(64); WAITV(0); writeA(1); issueB(1, 64);
  WAITLG();
  // in flight: B(1) 6 gloads

  int cur = 0;
  for (int t = 0; t < 16; ++t) {
    SBAR();                                  // tile t staged (B drained prev phase C)
    if (t + 2 < 16) issueA((t + 2) * 64);    // hidden under MFMA phase
#pragma unroll
    for (int ks = 0; ks < 2; ++ks) {
      const int slot = (ks * 4 + g) ^ (lo & 7);
      bf16x8 af[4];
#pragma unroll
      for (int mi = 0; mi < 4; ++mi)
        af[mi] = ld8(&As[cur][(wm * 64 + mi * 16 + lo) * 64 + slot * 8]);
#pragma unroll
      for (int w = 0; w < 3; ++w) {
        bf16x8 bvf[2];
#pragma unroll
        for (int ni = 0; ni < 2; ++ni)
          bvf[ni] = ld8(&Bs[cur][w][(wn * 32 + ni * 16 + lo) * 64 + slot * 8]);
#pragma unroll
        for (int mi = 0; mi < 4; ++mi)
#pragma unroll
          for (int ni = 0; ni < 2; ++ni)
            acc[w][mi][ni] = __builtin_amdgcn_mfma_f32_16x16x32_bf16(af[mi], bvf[ni], acc[w][mi][ni], 0, 0, 0);
      }
    }
    SBAR();                                  // buf cur free
    if (t + 2 < 16) {
      WAITV(0);                              // drains B(t+1) (1 rnd old) + A(t+2) (~MFMA-phase old)
      writeA(cur);                           // tile t+2 A into just-freed buf
      issueB(cur, (t + 2) * 64);
      WAITLG();                              // ds_writes visible before next-next barrier
    } else if (t + 1 < 16) {
      WAITV(0);                              // ensure B(t+1) landed
    }
    cur ^= 1;
  }

  // epilogue (r18 verified): col = lane&15 (n), row = g*4 + r (m)
#pragma unroll
  for (int w = 0; w < 3; ++w) {
    unsigned short* Cv = (w == 0) ? q_s : (w == 1) ? k_s : vt_s;
#pragma unroll
    for (int mi = 0; mi < 4; ++mi) {
#pragma unroll
      for (int ni = 0; ni < 2; ++ni) {
        const int gcol = n0 + wn * 32 + ni * 16 + lo;
        const int h = gcol >> 6, d = gcol & 63;
        if (w == 2) {
          const int s0 = m0 + wm * 64 + mi * 16 + g * 4;
          const int b = s0 >> 11, s = s0 & 2047;
          u16x4 pk;
#pragma unroll
          for (int r = 0; r < 4; ++r) pk[r] = f2bf(acc[w][mi][ni][r]);
          *reinterpret_cast<u16x4*>(&Cv[(((size_t)(b * 16 + h)) * 64 + d) * 2048 + s]) = pk;
        } else {
#pragma unroll
          for (int r = 0; r < 4; ++r) {
            const int grow = m0 + wm * 64 + mi * 16 + g * 4 + r;
            const int b = grow >> 11, s = grow & 2047;
            Cv[(((size_t)(b * 16 + h)) * 2048 + s) * 64 + d] = f2bf(acc[w][mi][ni][r]);
          }
        }
      }
    }
  }
}

// ---------- out-GEMM (r13/r18 verified body) ----------

__global__ __launch_bounds__(256) void gemm_out(
    const unsigned short* __restrict__ A,
    const unsigned short* __restrict__ wb,
    float* __restrict__ out) {
  const unsigned short* W = wb + (size_t)3 * 1048576;
  __shared__ unsigned short As[2][128 * 64];
  __shared__ unsigned short Bs[2][64 * 64];
  const int tid  = threadIdx.x;
  const int lane = tid & 63;
  const int g    = lane >> 4;
  const int lo   = lane & 15;
  const int wid  = tid >> 6;
  const int m0   = blockIdx.y * 128;
  const int n0   = blockIdx.x * 64;
  const int wm   = wid >> 1, wn = wid & 1;

  f32x4 acc[4][2] = {};

  auto stage = [&](int buf, int k0) {
#pragma unroll
    for (int i = 0; i < 4; ++i) {
      const int c   = i * 256 + tid;
      const int row = c >> 3, cc = c & 7;
      const int scc = cc ^ (row & 7);
      gload16(A + (size_t)(m0 + row) * 1024 + k0 + scc * 8, &As[buf][(i * 4 + wid) * 512]);
    }
#pragma unroll
    for (int i = 0; i < 2; ++i) {
      const int c   = i * 256 + tid;
      const int row = c >> 3, cc = c & 7;
      const int scc = cc ^ (row & 7);
      gload16(W + (size_t)(n0 + row) * 1024 + k0 + scc * 8, &Bs[buf][(i * 4 + wid) * 512]);
    }
  };

  stage(0, 0);
  stage(1, 64);
  int cur = 0;
  for (int t = 0; t < 16; ++t) {
    if (t < 15) WAITV(6); else WAITV(0);
    SBAR();
#pragma unroll
    for (int ks = 0; ks < 2; ++ks) {
      const int slot = (ks * 4 + g) ^ (lo & 7);
      bf16x8 af[4], bvf[2];
#pragma unroll
      for (int mi = 0; mi < 4; ++mi)
        af[mi] = ld8(&As[cur][(wm * 64 + mi * 16 + lo) * 64 + slot * 8]);
#pragma unroll
      for (int ni = 0; ni < 2; ++ni)
        bvf[ni] = ld8(&Bs[cur][(wn * 32 + ni * 16 + lo) * 64 + slot * 8]);
#pragma unroll
      for (int mi = 0; mi < 4; ++mi)
#pragma unroll
        for (int ni = 0; ni < 2; ++ni)
          acc[mi][ni] = __builtin_amdgcn_mfma_f32_16x16x32_bf16(af[mi], bvf[ni], acc[mi][ni], 0, 0, 0);
    }
    SBAR();
    if (t + 2 < 16) stage(cur, (t + 2) * 64);
    cur ^= 1;
  }

#pragma unroll
  for (int mi = 0; mi < 4; ++mi)
#pragma unroll
    for (int ni = 0; ni < 2; ++ni) {
      const int gcol = n0 + wn * 32 + ni * 16 + lo;
#pragma unroll
      for (int r = 0; r < 4; ++r) {
        const int grow = m0 + wm * 64 + mi * 16 + g * 4 + r;
        out[(size_t)grow * 1024 + gcol] = acc[mi][ni][r];
      }
    }
}

// ---------- flash attention (r12/r16, unchanged): KV-split x2, 512 blocks ----------

__global__ __launch_bounds__(512, 4) void attn_fwd(
    const unsigned short* __restrict__ Q,
    const unsigned short* __restrict__ K,
    const unsigned short* __restrict__ Vt,
    unsigned short* __restrict__ O) {
  __shared__ unsigned short Kl[2][128 * 64];    // [key 0..127][d-chunks swz]
  __shared__ unsigned short Vl[2][2][64 * 64];  // [buf][kh][d][key-chunks swz]
  const int tid  = threadIdx.x;
  const int lane = tid & 63;
  const int wid  = tid >> 6;      // 0..7
  const int qs   = wid & 3;       // q-subwave
  const int kh   = wid >> 2;      // kv-half
  const int q31  = lane & 31;
  const int hi   = lane >> 5;
  const int bi   = blockIdx.x;    // 0..511
  const int bh   = bi & 31;
  const int j    = (bi < 256) ? (15 - (bi >> 5)) : ((bi - 256) >> 5);
  const int b    = bh >> 4, h = bh & 15;

  const unsigned short* Qb = Q  + (size_t)bh * 2048 * 64;
  const unsigned short* Kb = K  + (size_t)bh * 2048 * 64;
  const unsigned short* Vb = Vt + (size_t)bh * 64 * 2048;
  const float SC = 0.125f * 1.4426950408889634f;  // scale * log2(e)

  auto stage = [&](int buf, int t) {
#pragma unroll
    for (int i = 0; i < 2; ++i) {                // K
      const int c   = i * 512 + tid;             // 0..1023
      const int row = c >> 3, cc = c & 7;
      const int scc = cc ^ (row & 7);
      gload16(Kb + (size_t)(t * 128 + row) * 64 + scc * 8, &Kl[buf][(i * 8 + wid) * 512]);
    }
#pragma unroll
    for (int i = 0; i < 2; ++i) {                // V half i
      const int d  = tid >> 3, cc = tid & 7;
      const int scc = cc ^ (d & 7);
      gload16(Vb + (size_t)d * 2048 + t * 128 + i * 64 + scc * 8, &Vl[buf][i][wid * 512]);
    }
  };

  const int R  = j + 1;
  const int qv = j * 128 + qs * 32 + q31;

  bf16x8 qf[4];
#pragma unroll
  for (int ds = 0; ds < 4; ++ds) {
    bf16x8 tq = ld8(Qb + (size_t)qv * 64 + ds * 16 + hi * 8);
#pragma unroll
    for (int jx = 0; jx < 8; ++jx) tq[jx] = (__bf16)((float)tq[jx] * SC);
    qf[ds] = tq;
  }

  f32x16 oacc[2] = {};
  float m = -1.0e30f;      // finite sentinel (NaN-safe merges)
  float l = 0.f;           // per-lane partial

  stage(0, 0);
  int buf = 0;

  for (int t = 0; t < R; ++t) {
    SBAR();                               // all waves done reading buf^1
    if (t + 1 < R) { stage(buf ^ 1, t + 1); WAITV(4); }
    else WAITV(0);
    SBAR();                               // tile-t loads (all waves) landed

    const bool lastt = (t == j);
    const bool skipw = lastt && (kh == 1) && (qs < 2);   // fully masked
    if (!skipw) {
      f32x16 sv[2];
      __builtin_amdgcn_s_setprio(1);
#pragma unroll
      for (int kt2 = 0; kt2 < 2; ++kt2) {
        const int row = kh * 64 + kt2 * 32 + q31;
        f32x16 a = {};
#pragma unroll
        for (int ds = 0; ds < 4; ++ds) {
          bf16x8 kf = ld8(&Kl[buf][row * 64 + ((ds * 2 + hi) ^ (row & 7)) * 8]);
          a = __builtin_amdgcn_mfma_f32_32x32x16_bf16(kf, qf[ds], a, 0, 0, 0);
        }
        sv[kt2] = a;
      }
      __builtin_amdgcn_s_setprio(0);

      const bool domask = lastt && !(kh == 0 && qs >= 2);
      float t0 = -1.0e30f, t1 = -1.0e30f, t2 = -1.0e30f, t3 = -1.0e30f;
      if (domask) {
#pragma unroll
        for (int kt2 = 0; kt2 < 2; ++kt2)
#pragma unroll
          for (int r = 0; r < 16; ++r) {
            float v = sv[kt2][r];
            const int key = t * 128 + kh * 64 + kt2 * 32 + (r & 3) + 8 * (r >> 2) + 4 * hi;
            if (key > qv) v = -INFINITY;
            sv[kt2][r] = v;
            if ((r & 3) == 0) t0 = fmaxf(t0, v);
            else if ((r & 3) == 1) t1 = fmaxf(t1, v);
            else if ((r & 3) == 2) t2 = fmaxf(t2, v);
            else t3 = fmaxf(t3, v);
          }
      } else {
#pragma unroll
        for (int kt2 = 0; kt2 < 2; ++kt2)
#pragma unroll
          for (int r = 0; r < 16; ++r) {
            const float v = sv[kt2][r];
            if ((r & 3) == 0) t0 = fmaxf(t0, v);
            else if ((r & 3) == 1) t1 = fmaxf(t1, v);
            else if ((r & 3) == 2) t2 = fmaxf(t2, v);
            else t3 = fmaxf(t3, v);
          }
      }
      const float tmax = fmaxf(fmaxf(t0, t1), fmaxf(t2, t3));

      if (!__all(tmax <= m + 8.f)) {
        float rmax = fmaxf(tmax, __shfl_xor(tmax, 32));
        const float mn   = fmaxf(m, rmax);
        const float corr = e2(m - mn);
        l *= corr;
#pragma unroll
        for (int dt = 0; dt < 2; ++dt)
#pragma unroll
          for (int r = 0; r < 16; ++r) oacc[dt][r] *= corr;
        m = mn;
      }

      float p0 = 0.f, p1 = 0.f, p2 = 0.f, p3 = 0.f;
#pragma unroll
      for (int kt2 = 0; kt2 < 2; ++kt2)
#pragma unroll
        for (int r = 0; r < 16; ++r) {
          const float p = e2(sv[kt2][r] - m);
          sv[kt2][r] = p;
          if ((r & 3) == 0) p0 += p;
          else if ((r & 3) == 1) p1 += p;
          else if ((r & 3) == 2) p2 += p;
          else p3 += p;
        }
      l += (p0 + p1) + (p2 + p3);

      unsigned int pw[4][4];
#pragma unroll
      for (int ks = 0; ks < 4; ++ks) {
        const int kt2 = ks >> 1, Rr = (ks & 1) * 8;
        unsigned int a0 = cvtpk(sv[kt2][Rr + 0], sv[kt2][Rr + 1]);
        unsigned int c0 = cvtpk(sv[kt2][Rr + 4], sv[kt2][Rr + 5]);
        unsigned int a1 = cvtpk(sv[kt2][Rr + 2], sv[kt2][Rr + 3]);
        unsigned int c1 = cvtpk(sv[kt2][Rr + 6], sv[kt2][Rr + 7]);
        asm("v_permlane32_swap_b32 %0, %1" : "+v"(a0), "+v"(c0));
        asm("v_permlane32_swap_b32 %0, %1" : "+v"(a1), "+v"(c1));
        pw[ks][0] = a0; pw[ks][1] = a1; pw[ks][2] = c0; pw[ks][3] = c1;
      }

      __builtin_amdgcn_s_setprio(1);
#pragma unroll
      for (int dt = 0; dt < 2; ++dt) {
        const int dl = dt * 32 + q31;
#pragma unroll
        for (int ks = 0; ks < 4; ++ks) {
          bf16x8 vfr = ld8(&Vl[buf][kh][dl * 64 + ((ks * 2 + hi) ^ (dl & 7)) * 8]);
          u32x4 t4 = {pw[ks][0], pw[ks][1], pw[ks][2], pw[ks][3]};
          bf16x8 pb = __builtin_bit_cast(bf16x8, t4);
          oacc[dt] = __builtin_amdgcn_mfma_f32_32x32x16_bf16(vfr, pb, oacc[dt], 0, 0, 0);
        }
      }
      __builtin_amdgcn_s_setprio(0);
    }

    buf ^= 1;
  }

  // ---- merge kh halves via LDS, kh0 writes O ----
  SBAR();
  float* VlF = (float*)&Vl[0][0][0];
  float* KlF = (float*)&Kl[0][0];
  const int mi = qs * 64 + lane;
  if (kh == 1) {
    *reinterpret_cast<f32x16*>(&VlF[mi * 32])      = oacc[0];
    *reinterpret_cast<f32x16*>(&VlF[mi * 32 + 16]) = oacc[1];
    KlF[mi * 2] = m; KlF[mi * 2 + 1] = l;
  }
  SBAR();
  if (kh == 0) {
    const f32x16 o1a = *reinterpret_cast<const f32x16*>(&VlF[mi * 32]);
    const f32x16 o1b = *reinterpret_cast<const f32x16*>(&VlF[mi * 32 + 16]);
    const float m1 = KlF[mi * 2], l1 = KlF[mi * 2 + 1];
    const float mm = fmaxf(m, m1);
    const float c0 = e2(m - mm), c1 = e2(m1 - mm);
    float lr = l * c0 + l1 * c1;
    lr += __shfl_xor(lr, 32);
    const float inv = 1.f / lr;
    const size_t obase = ((size_t)(b * 2048 + qv)) * 1024 + h * 64;
#pragma unroll
    for (int dt = 0; dt < 2; ++dt)
#pragma unroll
      for (int r4 = 0; r4 < 4; ++r4) {
        u16x4 pk;
#pragma unroll
        for (int e = 0; e < 4; ++e) {
          const int r = r4 * 4 + e;
          const float o1 = (dt == 0) ? o1a[r] : o1b[r];
          pk[e] = f2bf((oacc[dt][r] * c0 + o1 * c1) * inv);
        }
        *reinterpret_cast<u16x4*>(&O[obase + dt * 32 + r4 * 8 + hi * 4]) = pk;
      }
  }
}

// ---------- launch ----------

extern "C" void kernel_launch(void* const* d_in, const int* in_sizes, int n_in,
                              void* d_out, int out_size, void* d_ws, size_t ws_size,
                              hipStream_t stream) {
  const float* x  = (const float*)d_in[0];
  const float* Wq = (const float*)d_in[1];
  const float* Wk = (const float*)d_in[2];
  const float* Wv = (const float*)d_in[3];
  const float* Wo = (const float*)d_in[4];
  float* out = (float*)d_out;

  char* ws = (char*)d_ws;
  const size_t MiB = 1024 * 1024;
  unsigned short* a_s  = (unsigned short*)(ws);              // 8 MiB bf16 attn out
  unsigned short* w_bf = (unsigned short*)(ws + 8  * MiB);   // 4 x 2 MiB
  unsigned short* q_s  = (unsigned short*)(ws + 16 * MiB);   // 8 MiB
  unsigned short* k_s  = (unsigned short*)(ws + 24 * MiB);   // 8 MiB
  unsigned short* vt_s = (unsigned short*)(ws + 32 * MiB);   // 8 MiB

  cvt_inputs<<<2048, dim3(256), 0, stream>>>(Wq, Wk, Wv, Wo, w_bf);
  gemm_qkv<<<dim3(16, 32), dim3(256), 0, stream>>>(x, w_bf, q_s, k_s, vt_s);
  attn_fwd<<<512, dim3(512), 0, stream>>>(q_s, k_s, vt_s, a_s);
  gemm_out<<<dim3(16, 32), dim3(256), 0, stream>>>(a_s, w_bf, out);
}

// Round 20
// 89.329 us; speedup vs baseline: 1.1188x; 1.1188x over previous
//
#include <hip/hip_runtime.h>
#include <hip/hip_bf16.h>

typedef __bf16 bf16x8 __attribute__((ext_vector_type(8)));
typedef float  f32x4  __attribute__((ext_vector_type(4)));
typedef float  f32x16 __attribute__((ext_vector_type(16)));
typedef unsigned short u16x8 __attribute__((ext_vector_type(8)));
typedef unsigned short u16x4 __attribute__((ext_vector_type(4)));
typedef unsigned int   u32x4 __attribute__((ext_vector_type(4)));

#define WAITV(N) asm volatile("s_waitcnt vmcnt(" #N ")" ::: "memory")
#define SBAR()   do { __builtin_amdgcn_s_barrier(); asm volatile("" ::: "memory"); } while (0)

// ---------- helpers ----------

__device__ __forceinline__ unsigned short f2bf(float f) {
  return __builtin_bit_cast(unsigned short, (__bf16)f);  // RNE via v_cvt
}

__device__ __forceinline__ bf16x8 ld8(const unsigned short* p) {
  return __builtin_bit_cast(bf16x8, *reinterpret_cast<const u16x8*>(p));
}

// packed f32x2 -> bf16x2 (low = a, high = b)
__device__ __forceinline__ unsigned int cvtpk(float a, float b) {
  unsigned int r;
  asm("v_cvt_pk_bf16_f32 %0, %1, %2" : "=v"(r) : "v"(a), "v"(b));
  return r;
}

// raw v_exp_f32: 2^x in one transcendental instr
__device__ __forceinline__ float e2(float x) {
  float r;
  asm("v_exp_f32 %0, %1" : "=v"(r) : "v"(x));
  return r;
}

// async global->LDS, 16B per lane. lds base must be wave-uniform (HW adds lane*16).
__device__ __forceinline__ void gload16(const unsigned short* src, unsigned short* lds) {
  __builtin_amdgcn_global_load_lds(
      (const __attribute__((address_space(1))) unsigned int*)src,
      (__attribute__((address_space(3))) unsigned int*)lds,
      16, 0, 0);
}

// ---------- input conversion: f32 -> bf16 ----------

__global__ __launch_bounds__(256) void cvt_inputs(
    const float* __restrict__ x, const float* __restrict__ Wq,
    const float* __restrict__ Wk, const float* __restrict__ Wv,
    const float* __restrict__ Wo,
    unsigned short* __restrict__ xb, unsigned short* __restrict__ wb) {
  const int NXC = 4194304 / 8;
  const int NWC = 1048576 / 8;   // 131072 = 2^17
  const int total = NXC + 4 * NWC;
  for (int cid = blockIdx.x * 256 + threadIdx.x; cid < total; cid += gridDim.x * 256) {
    const float* s; unsigned short* d; int off;
    if (cid < NXC) { s = x; d = xb; off = cid * 8; }
    else {
      const int c2 = cid - NXC; const int w = c2 >> 17; const int o2 = c2 & (NWC - 1);
      s = (w == 0) ? Wq : (w == 1) ? Wk : (w == 2) ? Wv : Wo;
      d = wb + (size_t)w * 1048576;
      off = o2 * 8;
    }
    const f32x4 a  = *reinterpret_cast<const f32x4*>(s + off);
    const f32x4 b2 = *reinterpret_cast<const f32x4*>(s + off + 4);
    u16x8 o;
#pragma unroll
    for (int j = 0; j < 4; ++j) { o[j] = f2bf(a[j]); o[j + 4] = f2bf(b2[j]); }
    *reinterpret_cast<u16x8*>(d + off) = o;
  }
}

// ---------- fused QKV GEMM: stage x once, cycle 3 weight tiles ----------
// 128x64 tile per weight, BK=64 (16 K-steps), 256 threads, 2x2 waves.
// LDS: As 32 KB + Bs 3x16 KB = 80 KB -> 2 blocks/CU. Per step: 4 A-loads +
// 6 B-loads staged, 96 MFMA (3 weights x 32) -> 3x MFMA per barrier-pair vs
// split kernel, 3x less logical x traffic. Swizzle + counted vmcnt per r13.
// Outputs: Q,K in qk layout [(b*16+h)*2048+s]*64+d ; V transposed
// [(b*16+h)*64+d]*2048+s.

__global__ __launch_bounds__(256, 2) void gemm_qkv(
    const unsigned short* __restrict__ xb,
    const unsigned short* __restrict__ wb,
    unsigned short* __restrict__ q_s,
    unsigned short* __restrict__ k_s,
    unsigned short* __restrict__ vt_s) {
  __shared__ unsigned short As[2][128 * 64];      // 32 KB
  __shared__ unsigned short Bs[2][3][64 * 64];    // 48 KB
  const int tid  = threadIdx.x;
  const int lane = tid & 63;
  const int g    = lane >> 4;
  const int lo   = lane & 15;
  const int wid  = tid >> 6;
  const int m0   = blockIdx.y * 128;
  const int n0   = blockIdx.x * 64;
  const int wm   = wid >> 1, wn = wid & 1;

  f32x4 acc[3][4][2] = {};    // [weight][mi][ni]

  // stage 128x64 A once + 3 x 64x64 B; 8 chunks/row, source pre-swizzled
  auto stage = [&](int buf, int k0) {
#pragma unroll
    for (int i = 0; i < 4; ++i) {                // A: 1024 chunks / 256 thr
      const int c   = i * 256 + tid;
      const int row = c >> 3, cc = c & 7;
      const int scc = cc ^ (row & 7);
      gload16(xb + (size_t)(m0 + row) * 1024 + k0 + scc * 8, &As[buf][(i * 4 + wid) * 512]);
    }
#pragma unroll
    for (int w = 0; w < 3; ++w)
#pragma unroll
      for (int i = 0; i < 2; ++i) {              // B: 512 chunks per weight
        const int c   = i * 256 + tid;
        const int row = c >> 3, cc = c & 7;
        const int scc = cc ^ (row & 7);
        gload16(wb + (size_t)w * 1048576 + (size_t)(n0 + row) * 1024 + k0 + scc * 8,
                &Bs[buf][w][(i * 4 + wid) * 512]);
      }
  };

  stage(0, 0);
  stage(1, 64);
  int cur = 0;
  for (int t = 0; t < 16; ++t) {
    if (t < 15) WAITV(10); else WAITV(0);  // tile t landed; t+1's 10 in flight
    SBAR();
#pragma unroll
    for (int ks = 0; ks < 2; ++ks) {
      const int slot = (ks * 4 + g) ^ (lo & 7);
      bf16x8 af[4];
#pragma unroll
      for (int mi = 0; mi < 4; ++mi)
        af[mi] = ld8(&As[cur][(wm * 64 + mi * 16 + lo) * 64 + slot * 8]);
#pragma unroll
      for (int w = 0; w < 3; ++w) {
        bf16x8 bvf[2];
#pragma unroll
        for (int ni = 0; ni < 2; ++ni)
          bvf[ni] = ld8(&Bs[cur][w][(wn * 32 + ni * 16 + lo) * 64 + slot * 8]);
#pragma unroll
        for (int mi = 0; mi < 4; ++mi)
#pragma unroll
          for (int ni = 0; ni < 2; ++ni)
            acc[w][mi][ni] = __builtin_amdgcn_mfma_f32_16x16x32_bf16(af[mi], bvf[ni], acc[w][mi][ni], 0, 0, 0);
      }
    }
    SBAR();                                // all waves done reading buf cur
    if (t + 2 < 16) stage(cur, (t + 2) * 64);
    cur ^= 1;
  }

  // epilogue: C/D col = lane&15 (n), row = g*4 + r (m); w=0,1 -> qk layout,
  // w=2 -> v-transposed (s contiguous in r)
#pragma unroll
  for (int w = 0; w < 3; ++w) {
    unsigned short* Cv = (w == 0) ? q_s : (w == 1) ? k_s : vt_s;
#pragma unroll
    for (int mi = 0; mi < 4; ++mi) {
#pragma unroll
      for (int ni = 0; ni < 2; ++ni) {
        const int gcol = n0 + wn * 32 + ni * 16 + lo;
        const int h = gcol >> 6, d = gcol & 63;
        if (w == 2) {
          const int s0 = m0 + wm * 64 + mi * 16 + g * 4;
          const int b = s0 >> 11, s = s0 & 2047;
          u16x4 pk;
#pragma unroll
          for (int r = 0; r < 4; ++r) pk[r] = f2bf(acc[w][mi][ni][r]);
          *reinterpret_cast<u16x4*>(&Cv[(((size_t)(b * 16 + h)) * 64 + d) * 2048 + s]) = pk;
        } else {
#pragma unroll
          for (int r = 0; r < 4; ++r) {
            const int grow = m0 + wm * 64 + mi * 16 + g * 4 + r;
            const int b = grow >> 11, s = grow & 2047;
            Cv[(((size_t)(b * 16 + h)) * 2048 + s) * 64 + d] = f2bf(acc[w][mi][ni][r]);
          }
        }
      }
    }
  }
}

// ---------- out-GEMM (r13 verified body): C[m,n] = sum_k A[m,k]*W[n,k] ----------
// BM=128 x 64 tile, BK=64, 256 threads, 48 KB LDS (3 blocks/CU), counted vmcnt.

__global__ __launch_bounds__(256) void gemm_out(
    const unsigned short* __restrict__ A,
    const unsigned short* __restrict__ wb,
    float* __restrict__ out) {
  const unsigned short* W = wb + (size_t)3 * 1048576;
  __shared__ unsigned short As[2][128 * 64];
  __shared__ unsigned short Bs[2][64 * 64];
  const int tid  = threadIdx.x;
  const int lane = tid & 63;
  const int g    = lane >> 4;
  const int lo   = lane & 15;
  const int wid  = tid >> 6;
  const int m0   = blockIdx.y * 128;
  const int n0   = blockIdx.x * 64;
  const int wm   = wid >> 1, wn = wid & 1;

  f32x4 acc[4][2] = {};

  auto stage = [&](int buf, int k0) {
#pragma unroll
    for (int i = 0; i < 4; ++i) {
      const int c   = i * 256 + tid;
      const int row = c >> 3, cc = c & 7;
      const int scc = cc ^ (row & 7);
      gload16(A + (size_t)(m0 + row) * 1024 + k0 + scc * 8, &As[buf][(i * 4 + wid) * 512]);
    }
#pragma unroll
    for (int i = 0; i < 2; ++i) {
      const int c   = i * 256 + tid;
      const int row = c >> 3, cc = c & 7;
      const int scc = cc ^ (row & 7);
      gload16(W + (size_t)(n0 + row) * 1024 + k0 + scc * 8, &Bs[buf][(i * 4 + wid) * 512]);
    }
  };

  stage(0, 0);
  stage(1, 64);
  int cur = 0;
  for (int t = 0; t < 16; ++t) {
    if (t < 15) WAITV(6); else WAITV(0);
    SBAR();
#pragma unroll
    for (int ks = 0; ks < 2; ++ks) {
      const int slot = (ks * 4 + g) ^ (lo & 7);
      bf16x8 af[4], bvf[2];
#pragma unroll
      for (int mi = 0; mi < 4; ++mi)
        af[mi] = ld8(&As[cur][(wm * 64 + mi * 16 + lo) * 64 + slot * 8]);
#pragma unroll
      for (int ni = 0; ni < 2; ++ni)
        bvf[ni] = ld8(&Bs[cur][(wn * 32 + ni * 16 + lo) * 64 + slot * 8]);
#pragma unroll
      for (int mi = 0; mi < 4; ++mi)
#pragma unroll
        for (int ni = 0; ni < 2; ++ni)
          acc[mi][ni] = __builtin_amdgcn_mfma_f32_16x16x32_bf16(af[mi], bvf[ni], acc[mi][ni], 0, 0, 0);
    }
    SBAR();
    if (t + 2 < 16) stage(cur, (t + 2) * 64);
    cur ^= 1;
  }

#pragma unroll
  for (int mi = 0; mi < 4; ++mi)
#pragma unroll
    for (int ni = 0; ni < 2; ++ni) {
      const int gcol = n0 + wn * 32 + ni * 16 + lo;
#pragma unroll
      for (int r = 0; r < 4; ++r) {
        const int grow = m0 + wm * 64 + mi * 16 + g * 4 + r;
        out[(size_t)grow * 1024 + gcol] = acc[mi][ni][r];
      }
    }
}

// ---------- flash attention (r12/r16 pairing): KV-split x2, 512 blocks ----------

__global__ __launch_bounds__(512, 4) void attn_fwd(
    const unsigned short* __restrict__ Q,
    const unsigned short* __restrict__ K,
    const unsigned short* __restrict__ Vt,
    unsigned short* __restrict__ O) {
  __shared__ unsigned short Kl[2][128 * 64];    // [key 0..127][d-chunks swz]
  __shared__ unsigned short Vl[2][2][64 * 64];  // [buf][kh][d][key-chunks swz]
  const int tid  = threadIdx.x;
  const int lane = tid & 63;
  const int wid  = tid >> 6;      // 0..7
  const int qs   = wid & 3;       // q-subwave
  const int kh   = wid >> 2;      // kv-half
  const int q31  = lane & 31;
  const int hi   = lane >> 5;
  const int bi   = blockIdx.x;    // 0..511
  const int bh   = bi & 31;
  const int j    = (bi < 256) ? (15 - (bi >> 5)) : ((bi - 256) >> 5);
  const int b    = bh >> 4, h = bh & 15;

  const unsigned short* Qb = Q  + (size_t)bh * 2048 * 64;
  const unsigned short* Kb = K  + (size_t)bh * 2048 * 64;
  const unsigned short* Vb = Vt + (size_t)bh * 64 * 2048;
  const float SC = 0.125f * 1.4426950408889634f;  // scale * log2(e)

  auto stage = [&](int buf, int t) {
#pragma unroll
    for (int i = 0; i < 2; ++i) {                // K
      const int c   = i * 512 + tid;             // 0..1023
      const int row = c >> 3, cc = c & 7;
      const int scc = cc ^ (row & 7);
      gload16(Kb + (size_t)(t * 128 + row) * 64 + scc * 8, &Kl[buf][(i * 8 + wid) * 512]);
    }
#pragma unroll
    for (int i = 0; i < 2; ++i) {                // V half i
      const int d  = tid >> 3, cc = tid & 7;
      const int scc = cc ^ (d & 7);
      gload16(Vb + (size_t)d * 2048 + t * 128 + i * 64 + scc * 8, &Vl[buf][i][wid * 512]);
    }
  };

  const int R  = j + 1;
  const int qv = j * 128 + qs * 32 + q31;

  bf16x8 qf[4];
#pragma unroll
  for (int ds = 0; ds < 4; ++ds) {
    bf16x8 tq = ld8(Qb + (size_t)qv * 64 + ds * 16 + hi * 8);
#pragma unroll
    for (int jx = 0; jx < 8; ++jx) tq[jx] = (__bf16)((float)tq[jx] * SC);
    qf[ds] = tq;
  }

  f32x16 oacc[2] = {};
  float m = -1.0e30f;      // finite sentinel (NaN-safe merges)
  float l = 0.f;           // per-lane partial

  stage(0, 0);
  int buf = 0;

  for (int t = 0; t < R; ++t) {
    SBAR();                               // all waves done reading buf^1
    if (t + 1 < R) { stage(buf ^ 1, t + 1); WAITV(4); }
    else WAITV(0);
    SBAR();                               // tile-t loads (all waves) landed

    const bool lastt = (t == j);
    const bool skipw = lastt && (kh == 1) && (qs < 2);   // fully masked
    if (!skipw) {
      f32x16 sv[2];
      __builtin_amdgcn_s_setprio(1);
#pragma unroll
      for (int kt2 = 0; kt2 < 2; ++kt2) {
        const int row = kh * 64 + kt2 * 32 + q31;
        f32x16 a = {};
#pragma unroll
        for (int ds = 0; ds < 4; ++ds) {
          bf16x8 kf = ld8(&Kl[buf][row * 64 + ((ds * 2 + hi) ^ (row & 7)) * 8]);
          a = __builtin_amdgcn_mfma_f32_32x32x16_bf16(kf, qf[ds], a, 0, 0, 0);
        }
        sv[kt2] = a;
      }
      __builtin_amdgcn_s_setprio(0);

      const bool domask = lastt && !(kh == 0 && qs >= 2);
      float t0 = -1.0e30f, t1 = -1.0e30f, t2 = -1.0e30f, t3 = -1.0e30f;
      if (domask) {
#pragma unroll
        for (int kt2 = 0; kt2 < 2; ++kt2)
#pragma unroll
          for (int r = 0; r < 16; ++r) {
            float v = sv[kt2][r];
            const int key = t * 128 + kh * 64 + kt2 * 32 + (r & 3) + 8 * (r >> 2) + 4 * hi;
            if (key > qv) v = -INFINITY;
            sv[kt2][r] = v;
            if ((r & 3) == 0) t0 = fmaxf(t0, v);
            else if ((r & 3) == 1) t1 = fmaxf(t1, v);
            else if ((r & 3) == 2) t2 = fmaxf(t2, v);
            else t3 = fmaxf(t3, v);
          }
      } else {
#pragma unroll
        for (int kt2 = 0; kt2 < 2; ++kt2)
#pragma unroll
          for (int r = 0; r < 16; ++r) {
            const float v = sv[kt2][r];
            if ((r & 3) == 0) t0 = fmaxf(t0, v);
            else if ((r & 3) == 1) t1 = fmaxf(t1, v);
            else if ((r & 3) == 2) t2 = fmaxf(t2, v);
            else t3 = fmaxf(t3, v);
          }
      }
      const float tmax = fmaxf(fmaxf(t0, t1), fmaxf(t2, t3));

      if (!__all(tmax <= m + 8.f)) {
        float rmax = fmaxf(tmax, __shfl_xor(tmax, 32));
        const float mn   = fmaxf(m, rmax);
        const float corr = e2(m - mn);
        l *= corr;
#pragma unroll
        for (int dt = 0; dt < 2; ++dt)
#pragma unroll
          for (int r = 0; r < 16; ++r) oacc[dt][r] *= corr;
        m = mn;
      }

      float p0 = 0.f, p1 = 0.f, p2 = 0.f, p3 = 0.f;
#pragma unroll
      for (int kt2 = 0; kt2 < 2; ++kt2)
#pragma unroll
        for (int r = 0; r < 16; ++r) {
          const float p = e2(sv[kt2][r] - m);
          sv[kt2][r] = p;
          if ((r & 3) == 0) p0 += p;
          else if ((r & 3) == 1) p1 += p;
          else if ((r & 3) == 2) p2 += p;
          else p3 += p;
        }
      l += (p0 + p1) + (p2 + p3);

      unsigned int pw[4][4];
#pragma unroll
      for (int ks = 0; ks < 4; ++ks) {
        const int kt2 = ks >> 1, Rr = (ks & 1) * 8;
        unsigned int a0 = cvtpk(sv[kt2][Rr + 0], sv[kt2][Rr + 1]);
        unsigned int c0 = cvtpk(sv[kt2][Rr + 4], sv[kt2][Rr + 5]);
        unsigned int a1 = cvtpk(sv[kt2][Rr + 2], sv[kt2][Rr + 3]);
        unsigned int c1 = cvtpk(sv[kt2][Rr + 6], sv[kt2][Rr + 7]);
        asm("v_permlane32_swap_b32 %0, %1" : "+v"(a0), "+v"(c0));
        asm("v_permlane32_swap_b32 %0, %1" : "+v"(a1), "+v"(c1));
        pw[ks][0] = a0; pw[ks][1] = a1; pw[ks][2] = c0; pw[ks][3] = c1;
      }

      __builtin_amdgcn_s_setprio(1);
#pragma unroll
      for (int dt = 0; dt < 2; ++dt) {
        const int dl = dt * 32 + q31;
#pragma unroll
        for (int ks = 0; ks < 4; ++ks) {
          bf16x8 vfr = ld8(&Vl[buf][kh][dl * 64 + ((ks * 2 + hi) ^ (dl & 7)) * 8]);
          u32x4 t4 = {pw[ks][0], pw[ks][1], pw[ks][2], pw[ks][3]};
          bf16x8 pb = __builtin_bit_cast(bf16x8, t4);
          oacc[dt] = __builtin_amdgcn_mfma_f32_32x32x16_bf16(vfr, pb, oacc[dt], 0, 0, 0);
        }
      }
      __builtin_amdgcn_s_setprio(0);
    }

    buf ^= 1;
  }

  // ---- merge kh halves via LDS, kh0 writes O ----
  SBAR();
  float* VlF = (float*)&Vl[0][0][0];
  float* KlF = (float*)&Kl[0][0];
  const int mi = qs * 64 + lane;
  if (kh == 1) {
    *reinterpret_cast<f32x16*>(&VlF[mi * 32])      = oacc[0];
    *reinterpret_cast<f32x16*>(&VlF[mi * 32 + 16]) = oacc[1];
    KlF[mi * 2] = m; KlF[mi * 2 + 1] = l;
  }
  SBAR();
  if (kh == 0) {
    const f32x16 o1a = *reinterpret_cast<const f32x16*>(&VlF[mi * 32]);
    const f32x16 o1b = *reinterpret_cast<const f32x16*>(&VlF[mi * 32 + 16]);
    const float m1 = KlF[mi * 2], l1 = KlF[mi * 2 + 1];
    const float mm = fmaxf(m, m1);
    const float c0 = e2(m - mm), c1 = e2(m1 - mm);
    float lr = l * c0 + l1 * c1;
    lr += __shfl_xor(lr, 32);
    const float inv = 1.f / lr;
    const size_t obase = ((size_t)(b * 2048 + qv)) * 1024 + h * 64;
#pragma unroll
    for (int dt = 0; dt < 2; ++dt)
#pragma unroll
      for (int r4 = 0; r4 < 4; ++r4) {
        u16x4 pk;
#pragma unroll
        for (int e = 0; e < 4; ++e) {
          const int r = r4 * 4 + e;
          const float o1 = (dt == 0) ? o1a[r] : o1b[r];
          pk[e] = f2bf((oacc[dt][r] * c0 + o1 * c1) * inv);
        }
        *reinterpret_cast<u16x4*>(&O[obase + dt * 32 + r4 * 8 + hi * 4]) = pk;
      }
  }
}

// ---------- launch ----------

extern "C" void kernel_launch(void* const* d_in, const int* in_sizes, int n_in,
                              void* d_out, int out_size, void* d_ws, size_t ws_size,
                              hipStream_t stream) {
  const float* x  = (const float*)d_in[0];
  const float* Wq = (const float*)d_in[1];
  const float* Wk = (const float*)d_in[2];
  const float* Wv = (const float*)d_in[3];
  const float* Wo = (const float*)d_in[4];
  float* out = (float*)d_out;

  char* ws = (char*)d_ws;
  const size_t MiB = 1024 * 1024;
  unsigned short* x_bf = (unsigned short*)(ws);              // 8 MiB (aliased by a_s)
  unsigned short* a_s  = (unsigned short*)(ws);              // 8 MiB bf16 attn out
  unsigned short* w_bf = (unsigned short*)(ws + 8  * MiB);   // 4 x 2 MiB
  unsigned short* q_s  = (unsigned short*)(ws + 16 * MiB);   // 8 MiB
  unsigned short* k_s  = (unsigned short*)(ws + 24 * MiB);   // 8 MiB
  unsigned short* vt_s = (unsigned short*)(ws + 32 * MiB);   // 8 MiB

  cvt_inputs<<<2048, dim3(256), 0, stream>>>(x, Wq, Wk, Wv, Wo, x_bf, w_bf);
  gemm_qkv<<<dim3(16, 32), dim3(256), 0, stream>>>(x_bf, w_bf, q_s, k_s, vt_s);
  attn_fwd<<<512, dim3(512), 0, stream>>>(q_s, k_s, vt_s, a_s);
  gemm_out<<<dim3(16, 32), dim3(256), 0, stream>>>(a_s, w_bf, out);
}